// Round 2
// baseline (651.432 us; speedup 1.0000x reference)
//
#include <hip/hip_runtime.h>
#include <hip/hip_bf16.h>

#define NN 4096
#define FF 32
#define EE 65536
#define GG 13

typedef float floatx4 __attribute__((ext_vector_type(4)));
typedef __bf16 bf16x8 __attribute__((ext_vector_type(8)));
typedef short short8 __attribute__((ext_vector_type(8)));

__device__ inline unsigned short f2bf(float f) {
    unsigned u = __float_as_uint(f);
    u += 0x7FFFu + ((u >> 16) & 1u);          // RNE to bf16
    return (unsigned short)(u >> 16);
}

// ---------------- B-fragment prep kernels ----------------
// Bfrag layout: element (ks, t, c, kl) at ((ks*NTOT + t)*512 + c*32 + kl), bf16.
// ks = k/32 (K-step), t = col/16 (n-tile), c = col&15, kl = k&31.
// Lane l reads 8 contiguous bf16 at c=l&15, kl=(l>>4)*8 -> per-instr 1KB contiguous.

__global__ void k_prep1(const float* __restrict__ x, unsigned short* __restrict__ B) {
    int tid = blockIdx.x * 256 + threadIdx.x;           // < 4096*32
    int k = tid >> 5, col = tid & 31;
    float v = fabsf(x[tid]);
    B[(((k >> 5) * 2 + (col >> 4)) << 9) + ((col & 15) << 5) + (k & 31)] = f2bf(v);
}

__global__ void k_prep2(const float* __restrict__ P1, unsigned short* __restrict__ B) {
    int tid = blockIdx.x * 256 + threadIdx.x;           // < 4096*96
    int k = tid / 96, jf = tid % 96;
    int j = jf >> 5, f = jf & 31;
    float v = fabsf(P1[((1 + j) * NN + k) * FF + f]);   // |y1[j][k][f]|
    B[(((k >> 5) * 6 + (jf >> 4)) << 9) + ((jf & 15) << 5) + (k & 31)] = f2bf(v);
}

__global__ void k_prep3(const float* __restrict__ P2, unsigned short* __restrict__ B) {
    int tid = blockIdx.x * 256 + threadIdx.x;           // < 4096*288
    int k = tid / 288, cc = tid % 288;
    int k3 = cc / 96, jf = cc % 96;
    float v = fabsf(P2[((1 + k3) * NN + k) * 96 + jf]); // |y2[j][k3][k][f]|, col = k3*96+j*32+f
    B[(((k >> 5) * 18 + (cc >> 4)) << 9) + ((cc & 15) << 5) + (k & 31)] = f2bf(v);
}

// ---------------- Pass 1: barrier-free register-streaming A + fused bf16 pack ----
// Two prior variants (reg-prefetch + LDS coop stage; async global_load_lds dbuf)
// both sat at ~117 us / 2.3 TB/s with ALL pipes <10% busy. Common invariant: a
// per-chunk __syncthreads(), which drains vmcnt(0) including the just-issued
// next-chunk prefetch -> issue/drain convoy, phase-locked across resident blocks.
// This version has NO LDS staging and NO barrier in the K-loop: each wave streams
// its own A-fragments global->VGPR with an explicit 3-deep rotation (fully
// unrolled, indices static), so the compiler emits counted FIFO vmcnt waits and
// loads stay in flight across iterations. Lane (c15,q) loads 2x dwordx4 at
// row c15, col ksg*32+q*8: the f0/f1 pair covers 16 rows x 128B fully, so HBM
// bytes are unchanged vs the coop-staged version. K-step order per wave is
// ksg = wave + 8*i (identical accumulation order -> identical numerics).
// Apack layout: [mat][tile(256)][ks(128)][c15*32 + q*8 + j] shorts, mat stride 1<<24.
__global__ __launch_bounds__(512, 4) void k_pass1(const float* __restrict__ Umat,
                                                  const float* __restrict__ Psi,
                                                  const unsigned short* __restrict__ Bfrag,
                                                  float* __restrict__ Pout,
                                                  unsigned short* __restrict__ Apack) {
    __shared__ float cs[2][16 * 32];
    int tile = blockIdx.x, mat = blockIdx.y;
    const float* A = (mat == 0) ? Umat : (Psi + (size_t)(mat - 1) * NN * NN);
    int tid = threadIdx.x;
    int wave = tid >> 6, lane = tid & 63;
    int c15 = lane & 15, q = lane >> 4;

    const float* ga = A + ((size_t)tile * 16 + c15) * NN + q * 8;   // + ksg*32 floats
    const unsigned short* bbase = Bfrag + (c15 << 5) + (q << 3);
    unsigned short* apk = Apack + ((size_t)mat << 24) + (size_t)tile * 65536
                          + (c15 << 5) + (q << 3);

    floatx4 acc0 = {0.f, 0.f, 0.f, 0.f}, acc1 = {0.f, 0.f, 0.f, 0.f};
    floatx4 pf0[3], pf1[3];
    short8 pb0[3], pb1[3];

    // prologue: 3 K-steps in flight
#pragma unroll
    for (int d = 0; d < 3; d++) {
        int ksg = wave + d * 8;
        pf0[d] = *(const floatx4*)(ga + ksg * 32);
        pf1[d] = *(const floatx4*)(ga + ksg * 32 + 4);
        pb0[d] = *(const short8*)(bbase + (size_t)(ksg * 2 + 0) * 512);
        pb1[d] = *(const short8*)(bbase + (size_t)(ksg * 2 + 1) * 512);
    }

#pragma unroll
    for (int i = 0; i < 16; i++) {
        const int s = i % 3;                   // static under full unroll
        floatx4 f0 = pf0[s], f1 = pf1[s];
        short8 bv0 = pb0[s], bv1 = pb1[s];
        if (i < 13) {                          // refill slot with K-step i+3
            int kn = wave + (i + 3) * 8;
            pf0[s] = *(const floatx4*)(ga + kn * 32);
            pf1[s] = *(const floatx4*)(ga + kn * 32 + 4);
            pb0[s] = *(const short8*)(bbase + (size_t)(kn * 2 + 0) * 512);
            pb1[s] = *(const short8*)(bbase + (size_t)(kn * 2 + 1) * 512);
        }
        int ksg = wave + i * 8;
        short8 av;
        av[0]=f2bf(f0[0]); av[1]=f2bf(f0[1]); av[2]=f2bf(f0[2]); av[3]=f2bf(f0[3]);
        av[4]=f2bf(f1[0]); av[5]=f2bf(f1[1]); av[6]=f2bf(f1[2]); av[7]=f2bf(f1[3]);
        *(short8*)(apk + (size_t)ksg * 512) = av;
        bf16x8 ab = __builtin_bit_cast(bf16x8, av);
        acc0 = __builtin_amdgcn_mfma_f32_16x16x32_bf16(ab, __builtin_bit_cast(bf16x8, bv0), acc0, 0, 0, 0);
        acc1 = __builtin_amdgcn_mfma_f32_16x16x32_bf16(ab, __builtin_bit_cast(bf16x8, bv1), acc1, 0, 0, 0);
    }

    // reduce partial K-sums across 8 waves: two LDS regions, 4 serialization steps
    int half = wave & 1;
    floatx4 acc[2] = {acc0, acc1};
    for (int w2 = 0; w2 < 4; w2++) {
        if ((wave >> 1) == w2) {
#pragma unroll
            for (int t = 0; t < 2; t++)
#pragma unroll
                for (int r = 0; r < 4; r++) {
                    int idx = (q * 4 + r) * 32 + t * 16 + c15;
                    if (w2 == 0) cs[half][idx] = acc[t][r];
                    else cs[half][idx] += acc[t][r];
                }
        }
        __syncthreads();
    }
    float* orow = Pout + ((size_t)mat * NN + (size_t)tile * 16) * 32;
    for (int i = tid; i < 16 * 32; i += 512) orow[i] = cs[0][i] + cs[1][i];
}

// ---------------- Passes 2/3: pure pre-packed bf16 streamer ----------------
template <int NT, int NTOT>
__global__ __launch_bounds__(512) void k_passP(const unsigned short* __restrict__ Apack,
                                               const unsigned short* __restrict__ Bfrag,
                                               float* __restrict__ Pout) {
    constexpr int NC = NT * 16;
    constexpr int NCTOT = NTOT * 16;
    int tile = blockIdx.x;
    int mat = blockIdx.y;
    int cg = blockIdx.z;
    int tid = threadIdx.x;
    int wave = tid >> 6, lane = tid & 63;
    int c15 = lane & 15, q = lane >> 4;
    const unsigned short* ap = Apack + ((size_t)mat << 24) + (size_t)tile * 65536
                               + (size_t)(wave * 16) * 512 + (c15 << 5) + (q << 3);
    const unsigned short* bbase = Bfrag + (size_t)(wave * 16) * NTOT * 512
                                  + (size_t)(cg * NT) * 512 + (c15 << 5) + (q << 3);

    floatx4 acc[NT];
#pragma unroll
    for (int t = 0; t < NT; t++) acc[t] = (floatx4){0.f, 0.f, 0.f, 0.f};

    short8 af = *(const short8*)ap;
    short8 bv[NT];
#pragma unroll
    for (int t = 0; t < NT; t++) bv[t] = *(const short8*)(bbase + t * 512);

    for (int s = 0; s < 15; s++) {
        short8 af2 = *(const short8*)(ap + (s + 1) * 512);
        short8 bv2[NT];
        const unsigned short* bp = bbase + (size_t)(s + 1) * NTOT * 512;
#pragma unroll
        for (int t = 0; t < NT; t++) bv2[t] = *(const short8*)(bp + t * 512);
        bf16x8 ab = __builtin_bit_cast(bf16x8, af);
#pragma unroll
        for (int t = 0; t < NT; t++)
            acc[t] = __builtin_amdgcn_mfma_f32_16x16x32_bf16(
                ab, __builtin_bit_cast(bf16x8, bv[t]), acc[t], 0, 0, 0);
        af = af2;
#pragma unroll
        for (int t = 0; t < NT; t++) bv[t] = bv2[t];
    }
    {
        bf16x8 ab = __builtin_bit_cast(bf16x8, af);
#pragma unroll
        for (int t = 0; t < NT; t++)
            acc[t] = __builtin_amdgcn_mfma_f32_16x16x32_bf16(
                ab, __builtin_bit_cast(bf16x8, bv[t]), acc[t], 0, 0, 0);
    }

    __shared__ float cs[2][16 * NC];
    int half = wave & 1;
    for (int w2 = 0; w2 < 4; w2++) {
        if ((wave >> 1) == w2) {
#pragma unroll
            for (int t = 0; t < NT; t++)
#pragma unroll
                for (int r = 0; r < 4; r++) {
                    int idx = (q * 4 + r) * NC + t * 16 + c15;
                    if (w2 == 0) cs[half][idx] = acc[t][r];
                    else cs[half][idx] += acc[t][r];
                }
        }
        __syncthreads();
    }
    float* orow = Pout + ((size_t)mat * NN + (size_t)tile * 16) * NCTOT + cg * NC;
    for (int i = tid; i < 16 * NC; i += 512) {
        int r = i / NC, c = i % NC;
        orow[(size_t)r * NCTOT + c] = cs[0][i] + cs[1][i];
    }
}

// ---------------- GAT stage ----------------
// Fused h + attention logits: one wave per (g,n); lane = head*32+outfeat.
__global__ void k_hes(const float* __restrict__ P1, const float* __restrict__ P2,
                      const float* __restrict__ P3, const float* __restrict__ gatW,
                      const float* __restrict__ attS, const float* __restrict__ attD,
                      float* __restrict__ h, float* __restrict__ es,
                      float* __restrict__ ed) {
    int w = (blockIdx.x * 256 + threadIdx.x) >> 6;  // exactly 13*4096 waves
    int lane = threadIdx.x & 63;
    int g = w >> 12, n = w & 4095;
    const float* crow;
    if (g == 0) crow = P1 + (size_t)n * FF;
    else if (g <= 3) crow = P2 + (size_t)n * 96 + (g - 1) * 32;
    else {
        int j = (g - 4) / 3, k3 = (g - 4) % 3;
        crow = P3 + (size_t)n * 288 + k3 * 96 + j * 32;
    }
    const float* wcol = gatW + g * (32 * 64) + lane;
    float a = 0.f;
#pragma unroll
    for (int f = 0; f < 32; f++) a += crow[f] * wcol[f * 64];
    h[(size_t)w * 64 + lane] = a;
    float vs = a * attS[g * 64 + lane];
    float vd = a * attD[g * 64 + lane];
#pragma unroll
    for (int off = 16; off >= 1; off >>= 1) {
        vs += __shfl_down(vs, off, 32);
        vd += __shfl_down(vd, off, 32);
    }
    if ((lane & 31) == 0) {
        es[w * 2 + (lane >> 5)] = vs;
        ed[w * 2 + (lane >> 5)] = vd;
    }
}

// CSR build over dst (self-loops appended as nodes)
__global__ void k_hist(const int* __restrict__ ei, int* __restrict__ cnt) {
    int e = blockIdx.x * 256 + threadIdx.x;  // exactly EE+NN
    int d = (e < EE) ? ei[EE + e] : (e - EE);
    atomicAdd(&cnt[d], 1);
}

__global__ void k_scan(const int* __restrict__ cnt, int* __restrict__ offs,
                       int* __restrict__ cursor) {
    int lane = threadIdx.x;  // 64 threads, 1 block
    int base = lane * 64;
    int s = 0;
    for (int i = 0; i < 64; i++) s += cnt[base + i];
    int x = s;
    for (int d = 1; d < 64; d <<= 1) {
        int y = __shfl_up(x, d);
        if (lane >= d) x += y;
    }
    int run = x - s;  // exclusive prefix of per-lane totals
    for (int i = 0; i < 64; i++) {
        offs[base + i] = run;
        cursor[base + i] = run;
        run += cnt[base + i];
    }
}

__global__ void k_scatter(const int* __restrict__ ei, int* __restrict__ cursor,
                          int* __restrict__ csr) {
    int e = blockIdx.x * 256 + threadIdx.x;  // exactly EE+NN
    int s, d;
    if (e < EE) { s = ei[e]; d = ei[EE + e]; } else { s = d = e - EE; }
    int pos = atomicAdd(&cursor[d], 1);
    csr[pos] = s;
}

// One wave per (branch g, dst node n); lane = head*32 + feat. Online softmax,
// 2-deep software pipeline on the edge gather chain.
__global__ void k_gat(const float* __restrict__ h, const float* __restrict__ es,
                      const float* __restrict__ ed, const int* __restrict__ offs,
                      const int* __restrict__ cnt, const int* __restrict__ csr,
                      const float* __restrict__ gatb, float* __restrict__ gact) {
    int w = (blockIdx.x * 256 + threadIdx.x) >> 6;  // exactly 13*4096 waves
    int lane = threadIdx.x & 63, hh = lane >> 5;
    int g = w >> 12, n = w & 4095;
    float myed = ed[w * 2 + hh];
    float bias = gatb[g * 64 + lane];
    int start = offs[n], deg = cnt[n];   // deg >= 1 (self-loop)
    const float* hg = h + (size_t)g * NN * 64;
    const float* esg = es + (size_t)g * NN * 2;
    int sA = csr[start];
    int sB = (deg > 1) ? csr[start + 1] : 0;
    float hvA = hg[(size_t)sA * 64 + lane];
    float lgA = esg[sA * 2 + hh];
    float m = -INFINITY, z = 0.f, acc = 0.f;
    for (int i = 0; i < deg; i++) {
        int sC = (i + 2 < deg) ? csr[start + i + 2] : 0;
        float hvB = hg[(size_t)sB * 64 + lane];   // prefetch next (safe index)
        float lgB = esg[sB * 2 + hh];
        float lg = lgA + myed;
        lg = (lg > 0.f) ? lg : 0.2f * lg;               // leaky_relu(0.2)
        float nm = fmaxf(m, lg);
        float sc = __expf(m - nm);
        float we = __expf(lg - nm);
        z = z * sc + we;
        acc = acc * sc + we * hvA;
        m = nm;
        sA = sB; sB = sC; hvA = hvB; lgA = lgB;
    }
    float o = acc / (z + 1e-16f) + bias;
    o = (o > 0.f) ? o : (__expf(o) - 1.f);              // elu
    gact[(size_t)w * 64 + lane] = o;
}

// Branch MLP: feat[n][g*64+k] = elu( gact[g][n][:] . mlpW[g][:,k] + mlpb[g][k] )
__global__ void k_mlp(const float* __restrict__ gact, const float* __restrict__ mlpW,
                      const float* __restrict__ mlpb, float* __restrict__ feat) {
    int tid = blockIdx.x * 256 + threadIdx.x;  // exactly 13*4096*64
    int g = tid >> 18;
    int n = (tid & ((1 << 18) - 1)) >> 6;
    int k = tid & 63;
    const float* grow = gact + ((size_t)g * NN + n) * 64;
    const float* wc = mlpW + (size_t)g * 64 * 64 + k;
    float a = mlpb[g * 64 + k];
#pragma unroll 8
    for (int i = 0; i < 64; i++) a += grow[i] * wc[i * 64];
    a = (a > 0.f) ? a : (__expf(a) - 1.f);              // elu (pre-head)
    feat[(size_t)n * 832 + g * 64 + k] = a;
}

// Head: logits = feat @ outW + outb, then log_softmax. One wave per node.
__global__ void k_final(const float* __restrict__ feat, const float* __restrict__ oW,
                        const float* __restrict__ ob, float* __restrict__ out) {
    int w = (blockIdx.x * 256 + threadIdx.x) >> 6;  // exactly 4096 waves
    int lane = threadIdx.x & 63;
    float a[10];
#pragma unroll
    for (int c = 0; c < 10; c++) a[c] = 0.f;
    const float* frow = feat + (size_t)w * 832;
#pragma unroll
    for (int i = 0; i < 13; i++) {
        float v = frow[i * 64 + lane];
        const float* wp = oW + (i * 64 + lane) * 10;
#pragma unroll
        for (int c = 0; c < 10; c++) a[c] += v * wp[c];
    }
#pragma unroll
    for (int off = 32; off >= 1; off >>= 1)
#pragma unroll
        for (int c = 0; c < 10; c++) a[c] += __shfl_down(a[c], off);
    if (lane == 0) {
        float m = -INFINITY;
#pragma unroll
        for (int c = 0; c < 10; c++) { a[c] += ob[c]; m = fmaxf(m, a[c]); }
        float s = 0.f;
#pragma unroll
        for (int c = 0; c < 10; c++) s += __expf(a[c] - m);
        float lse = m + __logf(s);
#pragma unroll
        for (int c = 0; c < 10; c++) out[w * 10 + c] = a[c] - lse;
    }
}

extern "C" void kernel_launch(void* const* d_in, const int* in_sizes, int n_in,
                              void* d_out, int out_size, void* d_ws, size_t ws_size,
                              hipStream_t stream) {
    const float* x    = (const float*)d_in[0];
    const int*   ei   = (const int*)d_in[1];
    const float* U    = (const float*)d_in[2];
    const float* psi  = (const float*)d_in[3];
    const float* gatW = (const float*)d_in[4];
    const float* attS = (const float*)d_in[5];
    const float* attD = (const float*)d_in[6];
    const float* gatb = (const float*)d_in[7];
    const float* mlpW = (const float*)d_in[8];
    const float* mlpb = (const float*)d_in[9];
    const float* oW   = (const float*)d_in[10];
    const float* ob   = (const float*)d_in[11];
    float* out = (float*)d_out;

    char* ws = (char*)d_ws;
    size_t off = 0;
    auto alloc = [&](size_t bytes) { char* p = ws + off; off += (bytes + 255) & ~(size_t)255; return p; };
    unsigned short* Apack = (unsigned short*)alloc((size_t)4 * NN * NN * 2);  // 128 MB bf16 A-frags
    unsigned short* bf1 = (unsigned short*)alloc((size_t)NN * 32 * 2);
    float* P1           = (float*)alloc((size_t)4 * NN * 32 * 4);
    unsigned short* bf2 = (unsigned short*)alloc((size_t)NN * 96 * 2);
    float* P2           = (float*)alloc((size_t)4 * NN * 96 * 4);
    unsigned short* bf3 = (unsigned short*)alloc((size_t)NN * 288 * 2);
    float* P3           = (float*)alloc((size_t)NN * 288 * 4);
    float* h            = (float*)alloc((size_t)GG * NN * 64 * 4);
    float* es           = (float*)alloc((size_t)GG * NN * 2 * 4);
    float* ed           = (float*)alloc((size_t)GG * NN * 2 * 4);
    int* cnt            = (int*)alloc((size_t)NN * 4);
    int* offs           = (int*)alloc((size_t)NN * 4);
    int* cursor         = (int*)alloc((size_t)NN * 4);
    int* csr            = (int*)alloc((size_t)(EE + NN) * 4);
    float* gact         = (float*)alloc((size_t)GG * NN * 64 * 4);
    float* feat         = (float*)alloc((size_t)NN * 832 * 4);
    (void)ws_size; (void)in_sizes; (void)n_in; (void)out_size;

    // CSR build (independent of scattering passes)
    hipMemsetAsync(cnt, 0, NN * 4, stream);
    k_hist<<<(EE + NN) / 256, 256, 0, stream>>>(ei, cnt);
    k_scan<<<1, 64, 0, stream>>>(cnt, offs, cursor);
    k_scatter<<<(EE + NN) / 256, 256, 0, stream>>>(ei, cursor, csr);

    // Scattering passes
    k_prep1<<<(NN * 32) / 256, 256, 0, stream>>>(x, bf1);
    k_pass1<<<dim3(NN / 16, 4), 512, 0, stream>>>(U, psi, bf1, P1, Apack);
    k_prep2<<<(NN * 96) / 256, 256, 0, stream>>>(P1, bf2);
    k_passP<6, 6><<<dim3(NN / 16, 4, 1), 512, 0, stream>>>(Apack, bf2, P2);
    k_prep3<<<(NN * 288) / 256, 256, 0, stream>>>(P2, bf3);
    k_passP<6, 18><<<dim3(NN / 16, 1, 3), 512, 0, stream>>>(Apack, bf3, P3);

    // GAT stage
    k_hes<<<(GG * NN * 64) / 256, 256, 0, stream>>>(P1, P2, P3, gatW, attS, attD, h, es, ed);
    k_gat<<<(GG * NN * 64) / 256, 256, 0, stream>>>(h, es, ed, offs, cnt, csr, gatb, gact);
    k_mlp<<<(GG * NN * 64) / 256, 256, 0, stream>>>(gact, mlpW, mlpb, feat);
    k_final<<<(NN * 64) / 256, 256, 0, stream>>>(feat, oW, ob, out);
}

// Round 3
// 646.916 us; speedup vs baseline: 1.0070x; 1.0070x over previous
//
#include <hip/hip_runtime.h>
#include <hip/hip_bf16.h>

#define NN 4096
#define FF 32
#define EE 65536
#define GG 13

typedef float floatx4 __attribute__((ext_vector_type(4)));
typedef __bf16 bf16x8 __attribute__((ext_vector_type(8)));
typedef short short8 __attribute__((ext_vector_type(8)));

__device__ inline unsigned short f2bf(float f) {
    unsigned u = __float_as_uint(f);
    u += 0x7FFFu + ((u >> 16) & 1u);          // RNE to bf16
    return (unsigned short)(u >> 16);
}

// async global->LDS, 16B per lane; lds dest = wave-uniform base + lane*16
__device__ inline void gl2lds16(const float* g, float* l) {
    __builtin_amdgcn_global_load_lds(
        (__attribute__((address_space(1))) void*)(void*)(g),
        (__attribute__((address_space(3))) void*)(l), 16, 0, 0);
}

// ---------------- B-fragment prep kernels ----------------
// Bfrag layout: element (ks, t, c, kl) at ((ks*NTOT + t)*512 + c*32 + kl), bf16.
// ks = k/32 (K-step), t = col/16 (n-tile), c = col&15, kl = k&31.
// Lane l reads 8 contiguous bf16 at c=l&15, kl=(l>>4)*8 -> per-instr 1KB contiguous.

__global__ void k_prep1(const float* __restrict__ x, unsigned short* __restrict__ B) {
    int tid = blockIdx.x * 256 + threadIdx.x;           // < 4096*32
    int k = tid >> 5, col = tid & 31;
    float v = fabsf(x[tid]);
    B[(((k >> 5) * 2 + (col >> 4)) << 9) + ((col & 15) << 5) + (k & 31)] = f2bf(v);
}

__global__ void k_prep2(const float* __restrict__ P1, unsigned short* __restrict__ B) {
    int tid = blockIdx.x * 256 + threadIdx.x;           // < 4096*96
    int k = tid / 96, jf = tid % 96;
    int j = jf >> 5, f = jf & 31;
    float v = fabsf(P1[((1 + j) * NN + k) * FF + f]);   // |y1[j][k][f]|
    B[(((k >> 5) * 6 + (jf >> 4)) << 9) + ((jf & 15) << 5) + (k & 31)] = f2bf(v);
}

__global__ void k_prep3(const float* __restrict__ P2, unsigned short* __restrict__ B) {
    int tid = blockIdx.x * 256 + threadIdx.x;           // < 4096*288
    int k = tid / 288, cc = tid % 288;
    int k3 = cc / 96, jf = cc % 96;
    float v = fabsf(P2[((1 + k3) * NN + k) * 96 + jf]); // |y2[j][k3][k][f]|, col = k3*96+j*32+f
    B[(((k >> 5) * 18 + (cc >> 4)) << 9) + ((cc & 15) << 5) + (k & 31)] = f2bf(v);
}

// ---------------- Pass 1: async-LDS staging with COUNTED vmcnt + raw s_barrier ----
// History: (r0) coop-LDS+reg-prefetch, (r1) global_load_lds dbuf + __syncthreads,
// (r2) barrier-free 3-deep register rotation -- ALL ~118us / 2.3 TB/s, all pipes
// <6% busy. r2's VGPR=36 proves hipcc collapses source-level register pipelines
// (needs >=48 for the slots); r1's __syncthreads drains vmcnt(0) per chunk ->
// issue/drain convoy. Per guide m131-m141 + T3/T4: the only plain-HIP path is
// global_load_lds with loads held in flight ACROSS barriers via counted waits.
// This version = r1 skeleton, but the per-chunk barrier is
//   s_waitcnt vmcnt(3); s_barrier
// Pinned per-iter VMEM order: stage(c+1){2 gl2lds} | fence | pb{2} | store{1}
// -> vmcnt(3) retires exactly the stage of chunk c+1, keeping 3 newest in flight.
// Next-chunk staging issued at loop top thus spans the whole compute phase and
// the barrier (never drained to 0 in the loop).
// K-step/wave mapping identical to r1 (ksg = c*8 + wave) -> identical numerics.
// Apack layout: [mat][tile(256)][ks(128)][c15*32 + q*8 + j] shorts, mat stride 1<<24.
__global__ __launch_bounds__(512, 8) void k_pass1(const float* __restrict__ Umat,
                                                  const float* __restrict__ Psi,
                                                  const unsigned short* __restrict__ Bfrag,
                                                  float* __restrict__ Pout,
                                                  unsigned short* __restrict__ Apack) {
    __shared__ float abuf[2][16 * 256];       // 2 x 16 KB, linear rows (no pad)
    __shared__ float cs[2][16 * 32];
    int tile = blockIdx.x, mat = blockIdx.y;
    const float* A = (mat == 0) ? Umat : (Psi + (size_t)(mat - 1) * NN * NN);
    int tid = threadIdx.x;
    int wave = tid >> 6, lane = tid & 63;
    int c15 = lane & 15, q = lane >> 4;

    const float* atile = A + (size_t)tile * 16 * NN;
    const unsigned short* bbase = Bfrag + (c15 << 5) + (q << 3);
    unsigned short* apk = Apack + ((size_t)mat << 24) + (size_t)tile * 65536
                          + (c15 << 5) + (q << 3);

    // staging: wave w owns rows 2w, 2w+1; per-lane global addr pre-swizzled so the
    // linear LDS write lands element (row, ku^(row&7)) at unit (row*64 + ku^(row&7)).
    int r0 = 2 * wave, r1 = 2 * wave + 1;
    const float* g0 = atile + (size_t)r0 * NN + ((lane ^ (r0 & 7)) << 2);
    const float* g1 = atile + (size_t)r1 * NN + ((lane ^ (r1 & 7)) << 2);
    float* l0 = &abuf[0][wave * 512];          // wave-uniform LDS bases (row r0, then r1)
    float* l1 = &abuf[1][wave * 512];

    // compute-side swizzled LDS word offsets (two b128 reads per K-step)
    int swz = c15 & 7;
    int u0 = ((wave * 8 + q * 2 + 0) ^ swz) << 2;
    int u1 = ((wave * 8 + q * 2 + 1) ^ swz) << 2;
    int rowbase = c15 << 8;                    // c15 * 256 floats

    floatx4 acc0 = {0.f, 0.f, 0.f, 0.f}, acc1 = {0.f, 0.f, 0.f, 0.f};

    // prologue: chunk 0 -> buf0 (async), B-frags for c=0 -> regs
    gl2lds16(g0, l0);
    gl2lds16(g1, l0 + 256);
    asm volatile("" ::: "memory");             // pin stage before pb loads
    short8 pb0 = *(const short8*)(bbase + (size_t)(wave * 2 + 0) * 512);
    short8 pb1 = *(const short8*)(bbase + (size_t)(wave * 2 + 1) * 512);
    asm volatile("s_waitcnt vmcnt(2)" ::: "memory");   // chunk-0 stage done; pb in flight
    __builtin_amdgcn_s_barrier();
    __builtin_amdgcn_sched_barrier(0);

    for (int c = 0; c < 16; c++) {
        const float* rb = abuf[c & 1];
        if (c < 15) {                          // async-stage chunk c+1 into other buffer
            float* wbb = (c & 1) ? l0 : l1;    // base of abuf[(c+1)&1] for this wave
            gl2lds16(g0 + (size_t)(c + 1) * 256, wbb);
            gl2lds16(g1 + (size_t)(c + 1) * 256, wbb + 256);
        }
        asm volatile("" ::: "memory");         // pin stage before pb/store
        int ksg = c * 8 + wave;                // this wave's global K-step
        floatx4 f0 = *(const floatx4*)(rb + rowbase + u0);
        floatx4 f1 = *(const floatx4*)(rb + rowbase + u1);
        short8 bv0 = pb0, bv1 = pb1;
        if (c < 15) {                          // prefetch next chunk's B-frags
            pb0 = *(const short8*)(bbase + (size_t)((ksg + 8) * 2 + 0) * 512);
            pb1 = *(const short8*)(bbase + (size_t)((ksg + 8) * 2 + 1) * 512);
        }
        short8 av;
        av[0]=f2bf(f0[0]); av[1]=f2bf(f0[1]); av[2]=f2bf(f0[2]); av[3]=f2bf(f0[3]);
        av[4]=f2bf(f1[0]); av[5]=f2bf(f1[1]); av[6]=f2bf(f1[2]); av[7]=f2bf(f1[3]);
        *(short8*)(apk + (size_t)ksg * 512) = av;
        bf16x8 ab = __builtin_bit_cast(bf16x8, av);
        acc0 = __builtin_amdgcn_mfma_f32_16x16x32_bf16(ab, __builtin_bit_cast(bf16x8, bv0), acc0, 0, 0, 0);
        acc1 = __builtin_amdgcn_mfma_f32_16x16x32_bf16(ab, __builtin_bit_cast(bf16x8, bv1), acc1, 0, 0, 0);
        if (c < 15) {
            // stage(c+1){2} | pb{2} | store{1} are the <=5 newest VMEM ops;
            // vmcnt(3) retires stage(c+1), keeps pb+store in flight across barrier.
            asm volatile("s_waitcnt vmcnt(3)" ::: "memory");
            __builtin_amdgcn_s_barrier();
            __builtin_amdgcn_sched_barrier(0);
        }
    }

    // reduce partial K-sums across 8 waves: two LDS regions, 4 serialization steps
    int half = wave & 1;
    floatx4 acc[2] = {acc0, acc1};
    for (int w2 = 0; w2 < 4; w2++) {
        if ((wave >> 1) == w2) {
#pragma unroll
            for (int t = 0; t < 2; t++)
#pragma unroll
                for (int r = 0; r < 4; r++) {
                    int idx = (q * 4 + r) * 32 + t * 16 + c15;
                    if (w2 == 0) cs[half][idx] = acc[t][r];
                    else cs[half][idx] += acc[t][r];
                }
        }
        __syncthreads();
    }
    float* orow = Pout + ((size_t)mat * NN + (size_t)tile * 16) * 32;
    for (int i = tid; i < 16 * 32; i += 512) orow[i] = cs[0][i] + cs[1][i];
}

// ---------------- Passes 2/3: pure pre-packed bf16 streamer ----------------
template <int NT, int NTOT>
__global__ __launch_bounds__(512) void k_passP(const unsigned short* __restrict__ Apack,
                                               const unsigned short* __restrict__ Bfrag,
                                               float* __restrict__ Pout) {
    constexpr int NC = NT * 16;
    constexpr int NCTOT = NTOT * 16;
    int tile = blockIdx.x;
    int mat = blockIdx.y;
    int cg = blockIdx.z;
    int tid = threadIdx.x;
    int wave = tid >> 6, lane = tid & 63;
    int c15 = lane & 15, q = lane >> 4;
    const unsigned short* ap = Apack + ((size_t)mat << 24) + (size_t)tile * 65536
                               + (size_t)(wave * 16) * 512 + (c15 << 5) + (q << 3);
    const unsigned short* bbase = Bfrag + (size_t)(wave * 16) * NTOT * 512
                                  + (size_t)(cg * NT) * 512 + (c15 << 5) + (q << 3);

    floatx4 acc[NT];
#pragma unroll
    for (int t = 0; t < NT; t++) acc[t] = (floatx4){0.f, 0.f, 0.f, 0.f};

    short8 af = *(const short8*)ap;
    short8 bv[NT];
#pragma unroll
    for (int t = 0; t < NT; t++) bv[t] = *(const short8*)(bbase + t * 512);

    for (int s = 0; s < 15; s++) {
        short8 af2 = *(const short8*)(ap + (s + 1) * 512);
        short8 bv2[NT];
        const unsigned short* bp = bbase + (size_t)(s + 1) * NTOT * 512;
#pragma unroll
        for (int t = 0; t < NT; t++) bv2[t] = *(const short8*)(bp + t * 512);
        bf16x8 ab = __builtin_bit_cast(bf16x8, af);
#pragma unroll
        for (int t = 0; t < NT; t++)
            acc[t] = __builtin_amdgcn_mfma_f32_16x16x32_bf16(
                ab, __builtin_bit_cast(bf16x8, bv[t]), acc[t], 0, 0, 0);
        af = af2;
#pragma unroll
        for (int t = 0; t < NT; t++) bv[t] = bv2[t];
    }
    {
        bf16x8 ab = __builtin_bit_cast(bf16x8, af);
#pragma unroll
        for (int t = 0; t < NT; t++)
            acc[t] = __builtin_amdgcn_mfma_f32_16x16x32_bf16(
                ab, __builtin_bit_cast(bf16x8, bv[t]), acc[t], 0, 0, 0);
    }

    __shared__ float cs[2][16 * NC];
    int half = wave & 1;
    for (int w2 = 0; w2 < 4; w2++) {
        if ((wave >> 1) == w2) {
#pragma unroll
            for (int t = 0; t < NT; t++)
#pragma unroll
                for (int r = 0; r < 4; r++) {
                    int idx = (q * 4 + r) * NC + t * 16 + c15;
                    if (w2 == 0) cs[half][idx] = acc[t][r];
                    else cs[half][idx] += acc[t][r];
                }
        }
        __syncthreads();
    }
    float* orow = Pout + ((size_t)mat * NN + (size_t)tile * 16) * NCTOT + cg * NC;
    for (int i = tid; i < 16 * NC; i += 512) {
        int r = i / NC, c = i % NC;
        orow[(size_t)r * NCTOT + c] = cs[0][i] + cs[1][i];
    }
}

// ---------------- GAT stage ----------------
// Fused h + attention logits: one wave per (g,n); lane = head*32+outfeat.
__global__ void k_hes(const float* __restrict__ P1, const float* __restrict__ P2,
                      const float* __restrict__ P3, const float* __restrict__ gatW,
                      const float* __restrict__ attS, const float* __restrict__ attD,
                      float* __restrict__ h, float* __restrict__ es,
                      float* __restrict__ ed) {
    int w = (blockIdx.x * 256 + threadIdx.x) >> 6;  // exactly 13*4096 waves
    int lane = threadIdx.x & 63;
    int g = w >> 12, n = w & 4095;
    const float* crow;
    if (g == 0) crow = P1 + (size_t)n * FF;
    else if (g <= 3) crow = P2 + (size_t)n * 96 + (g - 1) * 32;
    else {
        int j = (g - 4) / 3, k3 = (g - 4) % 3;
        crow = P3 + (size_t)n * 288 + k3 * 96 + j * 32;
    }
    const float* wcol = gatW + g * (32 * 64) + lane;
    float a = 0.f;
#pragma unroll
    for (int f = 0; f < 32; f++) a += crow[f] * wcol[f * 64];
    h[(size_t)w * 64 + lane] = a;
    float vs = a * attS[g * 64 + lane];
    float vd = a * attD[g * 64 + lane];
#pragma unroll
    for (int off = 16; off >= 1; off >>= 1) {
        vs += __shfl_down(vs, off, 32);
        vd += __shfl_down(vd, off, 32);
    }
    if ((lane & 31) == 0) {
        es[w * 2 + (lane >> 5)] = vs;
        ed[w * 2 + (lane >> 5)] = vd;
    }
}

// CSR build over dst (self-loops appended as nodes)
__global__ void k_hist(const int* __restrict__ ei, int* __restrict__ cnt) {
    int e = blockIdx.x * 256 + threadIdx.x;  // exactly EE+NN
    int d = (e < EE) ? ei[EE + e] : (e - EE);
    atomicAdd(&cnt[d], 1);
}

__global__ void k_scan(const int* __restrict__ cnt, int* __restrict__ offs,
                       int* __restrict__ cursor) {
    int lane = threadIdx.x;  // 64 threads, 1 block
    int base = lane * 64;
    int s = 0;
    for (int i = 0; i < 64; i++) s += cnt[base + i];
    int x = s;
    for (int d = 1; d < 64; d <<= 1) {
        int y = __shfl_up(x, d);
        if (lane >= d) x += y;
    }
    int run = x - s;  // exclusive prefix of per-lane totals
    for (int i = 0; i < 64; i++) {
        offs[base + i] = run;
        cursor[base + i] = run;
        run += cnt[base + i];
    }
}

__global__ void k_scatter(const int* __restrict__ ei, int* __restrict__ cursor,
                          int* __restrict__ csr) {
    int e = blockIdx.x * 256 + threadIdx.x;  // exactly EE+NN
    int s, d;
    if (e < EE) { s = ei[e]; d = ei[EE + e]; } else { s = d = e - EE; }
    int pos = atomicAdd(&cursor[d], 1);
    csr[pos] = s;
}

// One wave per (branch g, dst node n); lane = head*32 + feat. Online softmax,
// 2-deep software pipeline on the edge gather chain.
__global__ void k_gat(const float* __restrict__ h, const float* __restrict__ es,
                      const float* __restrict__ ed, const int* __restrict__ offs,
                      const int* __restrict__ cnt, const int* __restrict__ csr,
                      const float* __restrict__ gatb, float* __restrict__ gact) {
    int w = (blockIdx.x * 256 + threadIdx.x) >> 6;  // exactly 13*4096 waves
    int lane = threadIdx.x & 63, hh = lane >> 5;
    int g = w >> 12, n = w & 4095;
    float myed = ed[w * 2 + hh];
    float bias = gatb[g * 64 + lane];
    int start = offs[n], deg = cnt[n];   // deg >= 1 (self-loop)
    const float* hg = h + (size_t)g * NN * 64;
    const float* esg = es + (size_t)g * NN * 2;
    int sA = csr[start];
    int sB = (deg > 1) ? csr[start + 1] : 0;
    float hvA = hg[(size_t)sA * 64 + lane];
    float lgA = esg[sA * 2 + hh];
    float m = -INFINITY, z = 0.f, acc = 0.f;
    for (int i = 0; i < deg; i++) {
        int sC = (i + 2 < deg) ? csr[start + i + 2] : 0;
        float hvB = hg[(size_t)sB * 64 + lane];   // prefetch next (safe index)
        float lgB = esg[sB * 2 + hh];
        float lg = lgA + myed;
        lg = (lg > 0.f) ? lg : 0.2f * lg;               // leaky_relu(0.2)
        float nm = fmaxf(m, lg);
        float sc = __expf(m - nm);
        float we = __expf(lg - nm);
        z = z * sc + we;
        acc = acc * sc + we * hvA;
        m = nm;
        sA = sB; sB = sC; hvA = hvB; lgA = lgB;
    }
    float o = acc / (z + 1e-16f) + bias;
    o = (o > 0.f) ? o : (__expf(o) - 1.f);              // elu
    gact[(size_t)w * 64 + lane] = o;
}

// Branch MLP: feat[n][g*64+k] = elu( gact[g][n][:] . mlpW[g][:,k] + mlpb[g][k] )
__global__ void k_mlp(const float* __restrict__ gact, const float* __restrict__ mlpW,
                      const float* __restrict__ mlpb, float* __restrict__ feat) {
    int tid = blockIdx.x * 256 + threadIdx.x;  // exactly 13*4096*64
    int g = tid >> 18;
    int n = (tid & ((1 << 18) - 1)) >> 6;
    int k = tid & 63;
    const float* grow = gact + ((size_t)g * NN + n) * 64;
    const float* wc = mlpW + (size_t)g * 64 * 64 + k;
    float a = mlpb[g * 64 + k];
#pragma unroll 8
    for (int i = 0; i < 64; i++) a += grow[i] * wc[i * 64];
    a = (a > 0.f) ? a : (__expf(a) - 1.f);              // elu (pre-head)
    feat[(size_t)n * 832 + g * 64 + k] = a;
}

// Head: logits = feat @ outW + outb, then log_softmax. One wave per node.
__global__ void k_final(const float* __restrict__ feat, const float* __restrict__ oW,
                        const float* __restrict__ ob, float* __restrict__ out) {
    int w = (blockIdx.x * 256 + threadIdx.x) >> 6;  // exactly 4096 waves
    int lane = threadIdx.x & 63;
    float a[10];
#pragma unroll
    for (int c = 0; c < 10; c++) a[c] = 0.f;
    const float* frow = feat + (size_t)w * 832;
#pragma unroll
    for (int i = 0; i < 13; i++) {
        float v = frow[i * 64 + lane];
        const float* wp = oW + (i * 64 + lane) * 10;
#pragma unroll
        for (int c = 0; c < 10; c++) a[c] += v * wp[c];
    }
#pragma unroll
    for (int off = 32; off >= 1; off >>= 1)
#pragma unroll
        for (int c = 0; c < 10; c++) a[c] += __shfl_down(a[c], off);
    if (lane == 0) {
        float m = -INFINITY;
#pragma unroll
        for (int c = 0; c < 10; c++) { a[c] += ob[c]; m = fmaxf(m, a[c]); }
        float s = 0.f;
#pragma unroll
        for (int c = 0; c < 10; c++) s += __expf(a[c] - m);
        float lse = m + __logf(s);
#pragma unroll
        for (int c = 0; c < 10; c++) out[w * 10 + c] = a[c] - lse;
    }
}

extern "C" void kernel_launch(void* const* d_in, const int* in_sizes, int n_in,
                              void* d_out, int out_size, void* d_ws, size_t ws_size,
                              hipStream_t stream) {
    const float* x    = (const float*)d_in[0];
    const int*   ei   = (const int*)d_in[1];
    const float* U    = (const float*)d_in[2];
    const float* psi  = (const float*)d_in[3];
    const float* gatW = (const float*)d_in[4];
    const float* attS = (const float*)d_in[5];
    const float* attD = (const float*)d_in[6];
    const float* gatb = (const float*)d_in[7];
    const float* mlpW = (const float*)d_in[8];
    const float* mlpb = (const float*)d_in[9];
    const float* oW   = (const float*)d_in[10];
    const float* ob   = (const float*)d_in[11];
    float* out = (float*)d_out;

    char* ws = (char*)d_ws;
    size_t off = 0;
    auto alloc = [&](size_t bytes) { char* p = ws + off; off += (bytes + 255) & ~(size_t)255; return p; };
    unsigned short* Apack = (unsigned short*)alloc((size_t)4 * NN * NN * 2);  // 128 MB bf16 A-frags
    unsigned short* bf1 = (unsigned short*)alloc((size_t)NN * 32 * 2);
    float* P1           = (float*)alloc((size_t)4 * NN * 32 * 4);
    unsigned short* bf2 = (unsigned short*)alloc((size_t)NN * 96 * 2);
    float* P2           = (float*)alloc((size_t)4 * NN * 96 * 4);
    unsigned short* bf3 = (unsigned short*)alloc((size_t)NN * 288 * 2);
    float* P3           = (float*)alloc((size_t)NN * 288 * 4);
    float* h            = (float*)alloc((size_t)GG * NN * 64 * 4);
    float* es           = (float*)alloc((size_t)GG * NN * 2 * 4);
    float* ed           = (float*)alloc((size_t)GG * NN * 2 * 4);
    int* cnt            = (int*)alloc((size_t)NN * 4);
    int* offs           = (int*)alloc((size_t)NN * 4);
    int* cursor         = (int*)alloc((size_t)NN * 4);
    int* csr            = (int*)alloc((size_t)(EE + NN) * 4);
    float* gact         = (float*)alloc((size_t)GG * NN * 64 * 4);
    float* feat         = (float*)alloc((size_t)NN * 832 * 4);
    (void)ws_size; (void)in_sizes; (void)n_in; (void)out_size;

    // CSR build (independent of scattering passes)
    hipMemsetAsync(cnt, 0, NN * 4, stream);
    k_hist<<<(EE + NN) / 256, 256, 0, stream>>>(ei, cnt);
    k_scan<<<1, 64, 0, stream>>>(cnt, offs, cursor);
    k_scatter<<<(EE + NN) / 256, 256, 0, stream>>>(ei, cursor, csr);

    // Scattering passes
    k_prep1<<<(NN * 32) / 256, 256, 0, stream>>>(x, bf1);
    k_pass1<<<dim3(NN / 16, 4), 512, 0, stream>>>(U, psi, bf1, P1, Apack);
    k_prep2<<<(NN * 96) / 256, 256, 0, stream>>>(P1, bf2);
    k_passP<6, 6><<<dim3(NN / 16, 4, 1), 512, 0, stream>>>(Apack, bf2, P2);
    k_prep3<<<(NN * 288) / 256, 256, 0, stream>>>(P2, bf3);
    k_passP<6, 18><<<dim3(NN / 16, 1, 3), 512, 0, stream>>>(Apack, bf3, P3);

    // GAT stage
    k_hes<<<(GG * NN * 64) / 256, 256, 0, stream>>>(P1, P2, P3, gatW, attS, attD, h, es, ed);
    k_gat<<<(GG * NN * 64) / 256, 256, 0, stream>>>(h, es, ed, offs, cnt, csr, gatb, gact);
    k_mlp<<<(GG * NN * 64) / 256, 256, 0, stream>>>(gact, mlpW, mlpb, feat);
    k_final<<<(NN * 64) / 256, 256, 0, stream>>>(feat, oW, ob, out);
}

// Round 4
// 627.598 us; speedup vs baseline: 1.0380x; 1.0308x over previous
//
#include <hip/hip_runtime.h>
#include <hip/hip_bf16.h>

#define NN 4096
#define FF 32
#define EE 65536
#define GG 13

typedef float floatx4 __attribute__((ext_vector_type(4)));
typedef __bf16 bf16x8 __attribute__((ext_vector_type(8)));
typedef short short8 __attribute__((ext_vector_type(8)));

__device__ inline unsigned short f2bf(float f) {
    unsigned u = __float_as_uint(f);
    u += 0x7FFFu + ((u >> 16) & 1u);          // RNE to bf16
    return (unsigned short)(u >> 16);
}

// async global->LDS, 16B per lane; lds dest = wave-uniform base + lane*16
__device__ inline void gl2lds16(const float* g, float* l) {
    __builtin_amdgcn_global_load_lds(
        (__attribute__((address_space(1))) void*)(void*)(g),
        (__attribute__((address_space(3))) void*)(l), 16, 0, 0);
}

// ---------------- B-fragment prep kernels ----------------
// Bfrag layout: element (ks, t, c, kl) at ((ks*NTOT + t)*512 + c*32 + kl), bf16.
// ks = k/32 (K-step), t = col/16 (n-tile), c = col&15, kl = k&31.
// Lane l reads 8 contiguous bf16 at c=l&15, kl=(l>>4)*8 -> per-instr 1KB contiguous.

__global__ void k_prep1(const float* __restrict__ x, unsigned short* __restrict__ B) {
    int tid = blockIdx.x * 256 + threadIdx.x;           // < 4096*32
    int k = tid >> 5, col = tid & 31;
    float v = fabsf(x[tid]);
    B[(((k >> 5) * 2 + (col >> 4)) << 9) + ((col & 15) << 5) + (k & 31)] = f2bf(v);
}

__global__ void k_prep2(const float* __restrict__ P1, unsigned short* __restrict__ B) {
    int tid = blockIdx.x * 256 + threadIdx.x;           // < 4096*96
    int k = tid / 96, jf = tid % 96;
    int j = jf >> 5, f = jf & 31;
    float v = fabsf(P1[((1 + j) * NN + k) * FF + f]);   // |y1[j][k][f]|
    B[(((k >> 5) * 6 + (jf >> 4)) << 9) + ((jf & 15) << 5) + (k & 31)] = f2bf(v);
}

__global__ void k_prep3(const float* __restrict__ P2, unsigned short* __restrict__ B) {
    int tid = blockIdx.x * 256 + threadIdx.x;           // < 4096*288
    int k = tid / 288, cc = tid % 288;
    int k3 = cc / 96, jf = cc % 96;
    float v = fabsf(P2[((1 + k3) * NN + k) * 96 + jf]); // |y2[j][k3][k][f]|, col = k3*96+j*32+f
    B[(((k >> 5) * 18 + (cc >> 4)) << 9) + ((cc & 15) << 5) + (k & 31)] = f2bf(v);
}

// ---------------- Pass 1: async-LDS staging, counted vmcnt + raw s_barrier ----
// NOTE (r0-r3): four structurally different schedules all measure ~118us /
// 2.3 TB/s with all pipes <6% busy. This one passed correctness; leaving as-is.
// Apack layout: [mat][tile(256)][ks(128)][c15*32 + q*8 + j] shorts, mat stride 1<<24.
__global__ __launch_bounds__(512, 8) void k_pass1(const float* __restrict__ Umat,
                                                  const float* __restrict__ Psi,
                                                  const unsigned short* __restrict__ Bfrag,
                                                  float* __restrict__ Pout,
                                                  unsigned short* __restrict__ Apack) {
    __shared__ float abuf[2][16 * 256];       // 2 x 16 KB, linear rows (no pad)
    __shared__ float cs[2][16 * 32];
    int tile = blockIdx.x, mat = blockIdx.y;
    const float* A = (mat == 0) ? Umat : (Psi + (size_t)(mat - 1) * NN * NN);
    int tid = threadIdx.x;
    int wave = tid >> 6, lane = tid & 63;
    int c15 = lane & 15, q = lane >> 4;

    const float* atile = A + (size_t)tile * 16 * NN;
    const unsigned short* bbase = Bfrag + (c15 << 5) + (q << 3);
    unsigned short* apk = Apack + ((size_t)mat << 24) + (size_t)tile * 65536
                          + (c15 << 5) + (q << 3);

    int r0 = 2 * wave, r1 = 2 * wave + 1;
    const float* g0 = atile + (size_t)r0 * NN + ((lane ^ (r0 & 7)) << 2);
    const float* g1 = atile + (size_t)r1 * NN + ((lane ^ (r1 & 7)) << 2);
    float* l0 = &abuf[0][wave * 512];
    float* l1 = &abuf[1][wave * 512];

    int swz = c15 & 7;
    int u0 = ((wave * 8 + q * 2 + 0) ^ swz) << 2;
    int u1 = ((wave * 8 + q * 2 + 1) ^ swz) << 2;
    int rowbase = c15 << 8;

    floatx4 acc0 = {0.f, 0.f, 0.f, 0.f}, acc1 = {0.f, 0.f, 0.f, 0.f};

    gl2lds16(g0, l0);
    gl2lds16(g1, l0 + 256);
    asm volatile("" ::: "memory");
    short8 pb0 = *(const short8*)(bbase + (size_t)(wave * 2 + 0) * 512);
    short8 pb1 = *(const short8*)(bbase + (size_t)(wave * 2 + 1) * 512);
    asm volatile("s_waitcnt vmcnt(2)" ::: "memory");
    __builtin_amdgcn_s_barrier();
    __builtin_amdgcn_sched_barrier(0);

    for (int c = 0; c < 16; c++) {
        const float* rb = abuf[c & 1];
        if (c < 15) {
            float* wbb = (c & 1) ? l0 : l1;
            gl2lds16(g0 + (size_t)(c + 1) * 256, wbb);
            gl2lds16(g1 + (size_t)(c + 1) * 256, wbb + 256);
        }
        asm volatile("" ::: "memory");
        int ksg = c * 8 + wave;
        floatx4 f0 = *(const floatx4*)(rb + rowbase + u0);
        floatx4 f1 = *(const floatx4*)(rb + rowbase + u1);
        short8 bv0 = pb0, bv1 = pb1;
        if (c < 15) {
            pb0 = *(const short8*)(bbase + (size_t)((ksg + 8) * 2 + 0) * 512);
            pb1 = *(const short8*)(bbase + (size_t)((ksg + 8) * 2 + 1) * 512);
        }
        short8 av;
        av[0]=f2bf(f0[0]); av[1]=f2bf(f0[1]); av[2]=f2bf(f0[2]); av[3]=f2bf(f0[3]);
        av[4]=f2bf(f1[0]); av[5]=f2bf(f1[1]); av[6]=f2bf(f1[2]); av[7]=f2bf(f1[3]);
        *(short8*)(apk + (size_t)ksg * 512) = av;
        bf16x8 ab = __builtin_bit_cast(bf16x8, av);
        acc0 = __builtin_amdgcn_mfma_f32_16x16x32_bf16(ab, __builtin_bit_cast(bf16x8, bv0), acc0, 0, 0, 0);
        acc1 = __builtin_amdgcn_mfma_f32_16x16x32_bf16(ab, __builtin_bit_cast(bf16x8, bv1), acc1, 0, 0, 0);
        if (c < 15) {
            asm volatile("s_waitcnt vmcnt(3)" ::: "memory");
            __builtin_amdgcn_s_barrier();
            __builtin_amdgcn_sched_barrier(0);
        }
    }

    int half = wave & 1;
    floatx4 acc[2] = {acc0, acc1};
    for (int w2 = 0; w2 < 4; w2++) {
        if ((wave >> 1) == w2) {
#pragma unroll
            for (int t = 0; t < 2; t++)
#pragma unroll
                for (int r = 0; r < 4; r++) {
                    int idx = (q * 4 + r) * 32 + t * 16 + c15;
                    if (w2 == 0) cs[half][idx] = acc[t][r];
                    else cs[half][idx] += acc[t][r];
                }
        }
        __syncthreads();
    }
    float* orow = Pout + ((size_t)mat * NN + (size_t)tile * 16) * 32;
    for (int i = tid; i < 16 * 32; i += 512) orow[i] = cs[0][i] + cs[1][i];
}

// ---------------- Passes 2/3: pre-packed bf16 streamer, M=32 row-pairs ----------
// r4 change: each block handles TWO 16-row tiles (2*tp, 2*tp+1). Every B fragment
// is loaded once and feeds 2 MFMAs (one per row-tile) -> B-side L2 traffic halves
// (<6,6>: ~770->385 MB; <6,18>: ~590->295 MB). Hand-prefetch removed (r2 proved
// the compiler collapses it anyway). Per-output accumulation order unchanged
// (same 16 s-steps per wave, same sequence) -> bit-identical numerics.
template <int NT, int NTOT>
__global__ __launch_bounds__(512) void k_passP(const unsigned short* __restrict__ Apack,
                                               const unsigned short* __restrict__ Bfrag,
                                               float* __restrict__ Pout) {
    constexpr int NC = NT * 16;
    constexpr int NCTOT = NTOT * 16;
    int tp = blockIdx.x;                      // tile pair: rows [2tp*16, 2tp*16+32)
    int mat = blockIdx.y;
    int cg = blockIdx.z;
    int tid = threadIdx.x;
    int wave = tid >> 6, lane = tid & 63;
    int c15 = lane & 15, q = lane >> 4;
    const unsigned short* ap0 = Apack + ((size_t)mat << 24) + (size_t)(2 * tp) * 65536
                                + (size_t)(wave * 16) * 512 + (c15 << 5) + (q << 3);
    const unsigned short* ap1 = ap0 + 65536;
    const unsigned short* bbase = Bfrag + (size_t)(wave * 16) * NTOT * 512
                                  + (size_t)(cg * NT) * 512 + (c15 << 5) + (q << 3);

    floatx4 acc0[NT], acc1[NT];
#pragma unroll
    for (int t = 0; t < NT; t++) {
        acc0[t] = (floatx4){0.f, 0.f, 0.f, 0.f};
        acc1[t] = (floatx4){0.f, 0.f, 0.f, 0.f};
    }

    for (int s = 0; s < 16; s++) {
        short8 a0 = *(const short8*)(ap0 + (size_t)s * 512);
        short8 a1 = *(const short8*)(ap1 + (size_t)s * 512);
        const unsigned short* bp = bbase + (size_t)s * NTOT * 512;
        bf16x8 ab0 = __builtin_bit_cast(bf16x8, a0);
        bf16x8 ab1 = __builtin_bit_cast(bf16x8, a1);
#pragma unroll
        for (int t = 0; t < NT; t++) {
            short8 bv = *(const short8*)(bp + t * 512);
            bf16x8 bb = __builtin_bit_cast(bf16x8, bv);
            acc0[t] = __builtin_amdgcn_mfma_f32_16x16x32_bf16(ab0, bb, acc0[t], 0, 0, 0);
            acc1[t] = __builtin_amdgcn_mfma_f32_16x16x32_bf16(ab1, bb, acc1[t], 0, 0, 0);
        }
    }

    __shared__ float cs[2][16 * NC];
    int half = wave & 1;

#define REDUCE_WRITE(ACC, TILE)                                                   \
    for (int w2 = 0; w2 < 4; w2++) {                                              \
        if ((wave >> 1) == w2) {                                                  \
            _Pragma("unroll")                                                     \
            for (int t = 0; t < NT; t++)                                          \
                _Pragma("unroll")                                                 \
                for (int r = 0; r < 4; r++) {                                     \
                    int idx = (q * 4 + r) * NC + t * 16 + c15;                    \
                    if (w2 == 0) cs[half][idx] = ACC[t][r];                       \
                    else cs[half][idx] += ACC[t][r];                              \
                }                                                                 \
        }                                                                         \
        __syncthreads();                                                          \
    }                                                                             \
    {                                                                             \
        float* orow = Pout + ((size_t)mat * NN + (size_t)(TILE) * 16) * NCTOT     \
                      + cg * NC;                                                  \
        for (int i = tid; i < 16 * NC; i += 512) {                                \
            int r = i / NC, c = i % NC;                                           \
            orow[(size_t)r * NCTOT + c] = cs[0][i] + cs[1][i];                    \
        }                                                                         \
    }

    REDUCE_WRITE(acc0, 2 * tp)
    __syncthreads();                          // cs reuse barrier between tiles
    REDUCE_WRITE(acc1, 2 * tp + 1)
#undef REDUCE_WRITE
}

// ---------------- GAT stage ----------------
// Fused h + attention logits: one wave per (g,n); lane = head*32+outfeat.
__global__ void k_hes(const float* __restrict__ P1, const float* __restrict__ P2,
                      const float* __restrict__ P3, const float* __restrict__ gatW,
                      const float* __restrict__ attS, const float* __restrict__ attD,
                      float* __restrict__ h, float* __restrict__ es,
                      float* __restrict__ ed) {
    int w = (blockIdx.x * 256 + threadIdx.x) >> 6;  // exactly 13*4096 waves
    int lane = threadIdx.x & 63;
    int g = w >> 12, n = w & 4095;
    const float* crow;
    if (g == 0) crow = P1 + (size_t)n * FF;
    else if (g <= 3) crow = P2 + (size_t)n * 96 + (g - 1) * 32;
    else {
        int j = (g - 4) / 3, k3 = (g - 4) % 3;
        crow = P3 + (size_t)n * 288 + k3 * 96 + j * 32;
    }
    const float* wcol = gatW + g * (32 * 64) + lane;
    float a = 0.f;
#pragma unroll
    for (int f = 0; f < 32; f++) a += crow[f] * wcol[f * 64];
    h[(size_t)w * 64 + lane] = a;
    float vs = a * attS[g * 64 + lane];
    float vd = a * attD[g * 64 + lane];
#pragma unroll
    for (int off = 16; off >= 1; off >>= 1) {
        vs += __shfl_down(vs, off, 32);
        vd += __shfl_down(vd, off, 32);
    }
    if ((lane & 31) == 0) {
        es[w * 2 + (lane >> 5)] = vs;
        ed[w * 2 + (lane >> 5)] = vd;
    }
}

// CSR build over dst (self-loops appended as nodes)
__global__ void k_hist(const int* __restrict__ ei, int* __restrict__ cnt) {
    int e = blockIdx.x * 256 + threadIdx.x;  // exactly EE+NN
    int d = (e < EE) ? ei[EE + e] : (e - EE);
    atomicAdd(&cnt[d], 1);
}

__global__ void k_scan(const int* __restrict__ cnt, int* __restrict__ offs,
                       int* __restrict__ cursor) {
    int lane = threadIdx.x;  // 64 threads, 1 block
    int base = lane * 64;
    int s = 0;
    for (int i = 0; i < 64; i++) s += cnt[base + i];
    int x = s;
    for (int d = 1; d < 64; d <<= 1) {
        int y = __shfl_up(x, d);
        if (lane >= d) x += y;
    }
    int run = x - s;  // exclusive prefix of per-lane totals
    for (int i = 0; i < 64; i++) {
        offs[base + i] = run;
        cursor[base + i] = run;
        run += cnt[base + i];
    }
}

__global__ void k_scatter(const int* __restrict__ ei, int* __restrict__ cursor,
                          int* __restrict__ csr) {
    int e = blockIdx.x * 256 + threadIdx.x;  // exactly EE+NN
    int s, d;
    if (e < EE) { s = ei[e]; d = ei[EE + e]; } else { s = d = e - EE; }
    int pos = atomicAdd(&cursor[d], 1);
    csr[pos] = s;
}

// One wave per (branch g, dst node n); lane = head*32 + feat. Online softmax,
// 2-deep software pipeline on the edge gather chain.
__global__ void k_gat(const float* __restrict__ h, const float* __restrict__ es,
                      const float* __restrict__ ed, const int* __restrict__ offs,
                      const int* __restrict__ cnt, const int* __restrict__ csr,
                      const float* __restrict__ gatb, float* __restrict__ gact) {
    int w = (blockIdx.x * 256 + threadIdx.x) >> 6;  // exactly 13*4096 waves
    int lane = threadIdx.x & 63, hh = lane >> 5;
    int g = w >> 12, n = w & 4095;
    float myed = ed[w * 2 + hh];
    float bias = gatb[g * 64 + lane];
    int start = offs[n], deg = cnt[n];   // deg >= 1 (self-loop)
    const float* hg = h + (size_t)g * NN * 64;
    const float* esg = es + (size_t)g * NN * 2;
    int sA = csr[start];
    int sB = (deg > 1) ? csr[start + 1] : 0;
    float hvA = hg[(size_t)sA * 64 + lane];
    float lgA = esg[sA * 2 + hh];
    float m = -INFINITY, z = 0.f, acc = 0.f;
    for (int i = 0; i < deg; i++) {
        int sC = (i + 2 < deg) ? csr[start + i + 2] : 0;
        float hvB = hg[(size_t)sB * 64 + lane];   // prefetch next (safe index)
        float lgB = esg[sB * 2 + hh];
        float lg = lgA + myed;
        lg = (lg > 0.f) ? lg : 0.2f * lg;               // leaky_relu(0.2)
        float nm = fmaxf(m, lg);
        float sc = __expf(m - nm);
        float we = __expf(lg - nm);
        z = z * sc + we;
        acc = acc * sc + we * hvA;
        m = nm;
        sA = sB; sB = sC; hvA = hvB; lgA = lgB;
    }
    float o = acc / (z + 1e-16f) + bias;
    o = (o > 0.f) ? o : (__expf(o) - 1.f);              // elu
    gact[(size_t)w * 64 + lane] = o;
}

// ---------------- Fused branch-MLP + head (r4: replaces k_mlp + k_final) -------
// One block per node: 13 waves, wave g computes feat[g][0..63] = elu(mlp) into
// LDS; wave 0 then does the head + log_softmax. Identical reduction orders to
// the old k_mlp/k_final -> bit-identical numerics; saves the 13.6 MB feat
// round-trip and one kernel launch.
__global__ __launch_bounds__(832) void k_out(const float* __restrict__ gact,
                                             const float* __restrict__ mlpW,
                                             const float* __restrict__ mlpb,
                                             const float* __restrict__ oW,
                                             const float* __restrict__ ob,
                                             float* __restrict__ out) {
    __shared__ float sf[832];
    int n = blockIdx.x;
    int g = threadIdx.x >> 6;        // 0..12
    int k = threadIdx.x & 63;
    const float* grow = gact + ((size_t)g * NN + n) * 64;
    const float* wc = mlpW + (size_t)g * 64 * 64 + k;
    float a = mlpb[g * 64 + k];
#pragma unroll 8
    for (int i = 0; i < 64; i++) a += grow[i] * wc[i * 64];
    a = (a > 0.f) ? a : (__expf(a) - 1.f);              // elu (pre-head)
    sf[g * 64 + k] = a;
    __syncthreads();
    if (g == 0) {
        float acc[10];
#pragma unroll
        for (int c = 0; c < 10; c++) acc[c] = 0.f;
#pragma unroll
        for (int i = 0; i < 13; i++) {
            float v = sf[i * 64 + k];
            const float* wp = oW + (i * 64 + k) * 10;
#pragma unroll
            for (int c = 0; c < 10; c++) acc[c] += v * wp[c];
        }
#pragma unroll
        for (int off = 32; off >= 1; off >>= 1)
#pragma unroll
            for (int c = 0; c < 10; c++) acc[c] += __shfl_down(acc[c], off);
        if (k == 0) {
            float m = -INFINITY;
#pragma unroll
            for (int c = 0; c < 10; c++) { acc[c] += ob[c]; m = fmaxf(m, acc[c]); }
            float s = 0.f;
#pragma unroll
            for (int c = 0; c < 10; c++) s += __expf(acc[c] - m);
            float lse = m + __logf(s);
#pragma unroll
            for (int c = 0; c < 10; c++) out[n * 10 + c] = acc[c] - lse;
        }
    }
}

extern "C" void kernel_launch(void* const* d_in, const int* in_sizes, int n_in,
                              void* d_out, int out_size, void* d_ws, size_t ws_size,
                              hipStream_t stream) {
    const float* x    = (const float*)d_in[0];
    const int*   ei   = (const int*)d_in[1];
    const float* U    = (const float*)d_in[2];
    const float* psi  = (const float*)d_in[3];
    const float* gatW = (const float*)d_in[4];
    const float* attS = (const float*)d_in[5];
    const float* attD = (const float*)d_in[6];
    const float* gatb = (const float*)d_in[7];
    const float* mlpW = (const float*)d_in[8];
    const float* mlpb = (const float*)d_in[9];
    const float* oW   = (const float*)d_in[10];
    const float* ob   = (const float*)d_in[11];
    float* out = (float*)d_out;

    char* ws = (char*)d_ws;
    size_t off = 0;
    auto alloc = [&](size_t bytes) { char* p = ws + off; off += (bytes + 255) & ~(size_t)255; return p; };
    unsigned short* Apack = (unsigned short*)alloc((size_t)4 * NN * NN * 2);  // 128 MB bf16 A-frags
    unsigned short* bf1 = (unsigned short*)alloc((size_t)NN * 32 * 2);
    float* P1           = (float*)alloc((size_t)4 * NN * 32 * 4);
    unsigned short* bf2 = (unsigned short*)alloc((size_t)NN * 96 * 2);
    float* P2           = (float*)alloc((size_t)4 * NN * 96 * 4);
    unsigned short* bf3 = (unsigned short*)alloc((size_t)NN * 288 * 2);
    float* P3           = (float*)alloc((size_t)NN * 288 * 4);
    float* h            = (float*)alloc((size_t)GG * NN * 64 * 4);
    float* es           = (float*)alloc((size_t)GG * NN * 2 * 4);
    float* ed           = (float*)alloc((size_t)GG * NN * 2 * 4);
    int* cnt            = (int*)alloc((size_t)NN * 4);
    int* offs           = (int*)alloc((size_t)NN * 4);
    int* cursor         = (int*)alloc((size_t)NN * 4);
    int* csr            = (int*)alloc((size_t)(EE + NN) * 4);
    float* gact         = (float*)alloc((size_t)GG * NN * 64 * 4);
    (void)ws_size; (void)in_sizes; (void)n_in; (void)out_size;

    // CSR build (independent of scattering passes)
    hipMemsetAsync(cnt, 0, NN * 4, stream);
    k_hist<<<(EE + NN) / 256, 256, 0, stream>>>(ei, cnt);
    k_scan<<<1, 64, 0, stream>>>(cnt, offs, cursor);
    k_scatter<<<(EE + NN) / 256, 256, 0, stream>>>(ei, cursor, csr);

    // Scattering passes
    k_prep1<<<(NN * 32) / 256, 256, 0, stream>>>(x, bf1);
    k_pass1<<<dim3(NN / 16, 4), 512, 0, stream>>>(U, psi, bf1, P1, Apack);
    k_prep2<<<(NN * 96) / 256, 256, 0, stream>>>(P1, bf2);
    k_passP<6, 6><<<dim3(NN / 32, 4, 1), 512, 0, stream>>>(Apack, bf2, P2);
    k_prep3<<<(NN * 288) / 256, 256, 0, stream>>>(P2, bf3);
    k_passP<6, 18><<<dim3(NN / 32, 1, 3), 512, 0, stream>>>(Apack, bf3, P3);

    // GAT stage
    k_hes<<<(GG * NN * 64) / 256, 256, 0, stream>>>(P1, P2, P3, gatW, attS, attD, h, es, ed);
    k_gat<<<(GG * NN * 64) / 256, 256, 0, stream>>>(h, es, ed, offs, cnt, csr, gatb, gact);
    k_out<<<NN, 832, 0, stream>>>(gact, mlpW, mlpb, oW, ob, out);
}